// Round 7
// baseline (1041.734 us; speedup 1.0000x reference)
//
#include <hip/hip_runtime.h>
#include <hip/hip_bf16.h>

// LTC RNN: B=512, T=1024, D=64, H=256, O=64.
// 32 blocks x 16 batch rows; T-loop in-kernel. Wf bf16 in registers (MFMA B-frags);
// A=[x_t|h_t] bf16 in swizzled LDS. fp32 master h-state in registers.
// R4 FIX: output dtype is FLOAT32 (reference is all-f32) — R2/R3 wrote bf16 into
// a float* buffer, which is what produced absmax ~1.7. MFMA lane maps are the
// m89/AMD-verified set (same as R2): A row=l&15,k=(l>>4)*8+e; C/D col=l&15,row=(l>>4)*4+reg.

typedef __attribute__((ext_vector_type(8))) short bf16x8;   // 8 bf16 (4 VGPRs)
typedef __attribute__((ext_vector_type(4))) float f32x4;
typedef __attribute__((ext_vector_type(2))) float f32x2;

#define T_STEPS 1024
#define D_IN    64
#define H_DIM   256
#define O_DIM   64
#define ROWS    16
#define NTHREADS 512
#define LDS_STRIDE 640        // bytes per A-row: 320 bf16 = [x(64) | h(256)]

__device__ __forceinline__ short f2bf(float x) {
    union { float f; unsigned u; } v; v.f = x;
    unsigned r = (v.u + 0x7FFFu + ((v.u >> 16) & 1u)) >> 16;   // RNE
    return (short)r;
}
__device__ __forceinline__ unsigned pack2(float a, float b) {
    return ((unsigned)(unsigned short)f2bf(b) << 16) | (unsigned)(unsigned short)f2bf(a);
}
__device__ __forceinline__ float sigm(float z) {
    float e = __builtin_amdgcn_exp2f(-1.4426950408889634f * z);   // exp(-z)
    return __builtin_amdgcn_rcpf(1.0f + e);
}

__global__ __launch_bounds__(NTHREADS, 2)
void ltc_kernel(const float* __restrict__ x_seq,  // [512,1024,64]
                const float* __restrict__ Wf,     // [256,320]
                const float* __restrict__ bf_,    // [256]
                const float* __restrict__ tau,    // [256]
                const float* __restrict__ Avec,   // [256]
                const float* __restrict__ Wo,     // [64,256]
                const float* __restrict__ bo,     // [64]
                float* __restrict__ out)          // [512,64] FLOAT32
{
    __shared__ alignas(64) char lds_raw[ROWS * LDS_STRIDE];   // 10240 B

    const int tid  = threadIdx.x;
    const int lane = tid & 63;
    const int w    = tid >> 6;        // wave 0..7
    const int lcol = lane & 15;
    const int lgrp = lane >> 4;       // 0..3
    const int brow0 = blockIdx.x * ROWS;
    const int jbase = w * 32;         // this wave's 32 j-columns

    // ---------- Wf as B-fragments: lane supplies B[k][n=lcol] = Wf[j][k],
    // j = jbase + nt*16 + lcol, k = kt*32 + lgrp*8 + e ----------
    bf16x8 bfrag[10][2];
    #pragma unroll
    for (int nt = 0; nt < 2; ++nt) {
        const int j = jbase + nt * 16 + lcol;
        const float* wrow = Wf + j * (D_IN + H_DIM);
        #pragma unroll
        for (int kt = 0; kt < 10; ++kt) {
            const int k0 = kt * 32 + lgrp * 8;
            f32x4 w0 = *(const f32x4*)(wrow + k0);
            f32x4 w1 = *(const f32x4*)(wrow + k0 + 4);
            bf16x8 b;
            b[0] = f2bf(w0[0]); b[1] = f2bf(w0[1]); b[2] = f2bf(w0[2]); b[3] = f2bf(w0[3]);
            b[4] = f2bf(w1[0]); b[5] = f2bf(w1[1]); b[6] = f2bf(w1[2]); b[7] = f2bf(w1[3]);
            bfrag[kt][nt] = b;
        }
    }

    // per-lane constants for the j this lane owns (C/D col = lane&15)
    const float dt = 0.1f;
    float bias[2], ctau[2], cA[2];
    #pragma unroll
    for (int nt = 0; nt < 2; ++nt) {
        const int j = jbase + nt * 16 + lcol;
        bias[nt] = bf_[j];
        ctau[nt] = 1.0f - dt * __builtin_amdgcn_rcpf(__expf(tau[j])); // 1 - dt/exp(tau)
        cA[nt]   = dt * Avec[j];
    }

    // ---------- LDS zero-init (h0 = 0), then stage x_0 ----------
    for (int i = tid; i < (ROWS * LDS_STRIDE) / 4; i += NTHREADS)
        ((unsigned*)lds_raw)[i] = 0u;
    __syncthreads();

    const int xrow = tid >> 5;        // 0..15
    const int xpos = tid & 31;        // 0..31, 2 floats each
    const float* xbase = x_seq + ((size_t)(brow0 + xrow) * T_STEPS) * D_IN + xpos * 2;
    const int xbyte = xrow * LDS_STRIDE + ((xpos * 4) ^ ((xrow & 7) << 4));
    {
        f32x2 x0 = *(const f32x2*)(xbase);
        *(unsigned*)(lds_raw + xbyte) = pack2(x0[0], x0[1]);
    }
    __syncthreads();

    // A-frag reads: lane reads row m = lcol, k = kt*32 + lgrp*8 + e
    const int arow = lcol;
    const char* abase = lds_raw + arow * LDS_STRIDE;
    const int aswz = (arow & 7) << 4;

    // fp32 master state: h[nt][r] for (row m = lgrp*4+r, col j = jbase+nt*16+lcol)
    float h0[4] = {0.f, 0.f, 0.f, 0.f};
    float h1[4] = {0.f, 0.f, 0.f, 0.f};

    for (int t = 0; t < T_STEPS; ++t) {
        const int tn = (t + 1 < T_STEPS) ? (t + 1) : (T_STEPS - 1);
        f32x2 xv = *(const f32x2*)(xbase + (size_t)tn * D_IN);   // prefetch x_{t+1}

        bf16x8 afrag[10];
        #pragma unroll
        for (int kt = 0; kt < 10; ++kt) {
            const int off = (kt * 64 + lgrp * 16) ^ aswz;
            afrag[kt] = *(const bf16x8*)(abase + off);
        }

        f32x4 acc0 = { bias[0], bias[0], bias[0], bias[0] };
        f32x4 acc1 = { bias[1], bias[1], bias[1], bias[1] };
        #pragma unroll
        for (int kt = 0; kt < 10; ++kt) {
            acc0 = __builtin_amdgcn_mfma_f32_16x16x32_bf16(afrag[kt], bfrag[kt][0], acc0, 0, 0, 0);
            acc1 = __builtin_amdgcn_mfma_f32_16x16x32_bf16(afrag[kt], bfrag[kt][1], acc1, 0, 0, 0);
        }

        // epilogue: f = sigmoid(z); h = h*(ctau - dt*f) + (dt*A)*f
        short hb0[4], hb1[4];
        #pragma unroll
        for (int r = 0; r < 4; ++r) {
            float f0 = sigm(acc0[r]);
            h0[r] = h0[r] * (ctau[0] - dt * f0) + cA[0] * f0;
            hb0[r] = f2bf(h0[r]);
            float f1 = sigm(acc1[r]);
            h1[r] = h1[r] * (ctau[1] - dt * f1) + cA[1] * f1;
            hb1[r] = f2bf(h1[r]);
        }

        __syncthreads();   // all waves done reading A_lds for step t

        // write h_{t+1} (bf16) at (m = lgrp*4+r, j = jbase + nt*16 + lcol), swizzled
        #pragma unroll
        for (int r = 0; r < 4; ++r) {
            const int m = lgrp * 4 + r;
            const int msw = (m & 7) << 4;
            const int kb0 = 2 * D_IN + 2 * (jbase + 0 * 16 + lcol);
            const int kb1 = 2 * D_IN + 2 * (jbase + 1 * 16 + lcol);
            *(short*)(lds_raw + m * LDS_STRIDE + (kb0 ^ msw)) = hb0[r];
            *(short*)(lds_raw + m * LDS_STRIDE + (kb1 ^ msw)) = hb1[r];
        }
        *(unsigned*)(lds_raw + xbyte) = pack2(xv[0], xv[1]);   // stage x_{t+1}

        __syncthreads();   // staging complete
    }

    // ---------- out = h_T @ Wo^T + bo ; h_T (bf16) in A_lds; f32 stores ----------
    if (w < 4) {
        bf16x8 ha[8];
        #pragma unroll
        for (int kt = 0; kt < 8; ++kt) {
            const int off = (2 * D_IN + kt * 64 + lgrp * 16) ^ aswz;
            ha[kt] = *(const bf16x8*)(abase + off);
        }
        const int o = w * 16 + lcol;              // lane supplies Wo[o][k]; C/D col -> same o
        const float* worow = Wo + o * H_DIM;
        const float bov = bo[o];
        f32x4 acc = { bov, bov, bov, bov };
        #pragma unroll
        for (int kt = 0; kt < 8; ++kt) {
            const int k0 = kt * 32 + lgrp * 8;
            f32x4 w0 = *(const f32x4*)(worow + k0);
            f32x4 w1 = *(const f32x4*)(worow + k0 + 4);
            bf16x8 b;
            b[0] = f2bf(w0[0]); b[1] = f2bf(w0[1]); b[2] = f2bf(w0[2]); b[3] = f2bf(w0[3]);
            b[4] = f2bf(w1[0]); b[5] = f2bf(w1[1]); b[6] = f2bf(w1[2]); b[7] = f2bf(w1[3]);
            acc = __builtin_amdgcn_mfma_f32_16x16x32_bf16(ha[kt], b, acc, 0, 0, 0);
        }
        #pragma unroll
        for (int r = 0; r < 4; ++r) {
            const int m = lgrp * 4 + r;           // C/D row = (lane>>4)*4 + reg
            out[(size_t)(brow0 + m) * O_DIM + o] = acc[r];
        }
    }
}

extern "C" void kernel_launch(void* const* d_in, const int* in_sizes, int n_in,
                              void* d_out, int out_size, void* d_ws, size_t ws_size,
                              hipStream_t stream) {
    const float* x_seq = (const float*)d_in[0];
    const float* Wf    = (const float*)d_in[1];
    const float* bf_   = (const float*)d_in[2];
    const float* tau   = (const float*)d_in[3];
    const float* Avec  = (const float*)d_in[4];
    const float* Wo    = (const float*)d_in[5];
    const float* bo    = (const float*)d_in[6];
    float* out = (float*)d_out;   // reference output dtype is float32

    ltc_kernel<<<512 / ROWS, NTHREADS, 0, stream>>>(x_seq, Wf, bf_, tau, Avec, Wo, bo, out);
}